// Round 9
// baseline (511.406 us; speedup 1.0000x reference)
//
#include <hip/hip_runtime.h>
#include <hip/hip_bf16.h>

typedef __attribute__((ext_vector_type(8)))  short s8v;   // 8 bf16
typedef __attribute__((ext_vector_type(4)))  float f4v;   // 16x16 C/D
typedef _Float16 h4 __attribute__((ext_vector_type(4)));  // 4 f16

constexpr int Dd   = 256;
constexpr int NCn  = 128;
constexpr int DDn  = 65536;
constexpr int PPn  = 4 * DDn;
constexpr size_t TB = (size_t)NCn * 4096;   // 524288 elems per token-tile
constexpr float EPSf = 1.1920929e-07f;

__device__ __forceinline__ float sigm(float x){ return 1.0f/(1.0f + expf(-x)); }
__device__ __forceinline__ float silu_(float x){ return x * sigm(x); }

__device__ __forceinline__ unsigned short f2b(float x){
    __hip_bfloat16 b = __float2bfloat16(x);
    unsigned short u; __builtin_memcpy(&u, &b, 2); return u;
}
__device__ __forceinline__ unsigned short f2hu(float x){
    _Float16 h = (_Float16)x;
    unsigned short u; __builtin_memcpy(&u, &h, 2); return u;
}
__device__ __forceinline__ float hu2f(unsigned short u){
    _Float16 h; __builtin_memcpy(&h, &u, 2); return (float)h;
}
__device__ __forceinline__ h4 ldh4(const unsigned short* p){
    h4 r; __builtin_memcpy(&r, p, 8); return r;
}

// grid barrier: monotonic counter, release-add + relaxed-load spin (device scope)
__device__ __forceinline__ void gsync(unsigned* bar){
    __syncthreads();
    if (threadIdx.x == 0){
        __threadfence();
        unsigned old = atomicAdd(bar, 1u);
        unsigned goal = (old/256u + 1u)*256u;
        while (__hip_atomic_load(bar, __ATOMIC_RELAXED, __HIP_MEMORY_SCOPE_AGENT) < goal)
            __builtin_amdgcn_s_sleep(4);
        __threadfence();
    }
    __syncthreads();
}

// 16x256 @ 256x16 slice
__device__ __forceinline__ f4v mm_core(const unsigned short* __restrict__ Arow,
                                       const unsigned short* __restrict__ Brow){
    s8v a[8], b[8];
    #pragma unroll
    for (int i = 0; i < 8; ++i) a[i] = *(const s8v*)(Arow + i*32);
    #pragma unroll
    for (int i = 0; i < 8; ++i) b[i] = *(const s8v*)(Brow + i*32);
    f4v acc = {0.f,0.f,0.f,0.f};
    #pragma unroll
    for (int i = 0; i < 8; ++i)
        acc = __builtin_amdgcn_mfma_f32_16x16x32_bf16(a[i], b[i], acc, 0, 0, 0);
    return acc;
}

__global__ __launch_bounds__(256, 1) void kchain(
        const float* __restrict__ seq, const float* __restrict__ wsn,
        const float* __restrict__ wrn, const float* __restrict__ wpost,
        const float* __restrict__ Wq, const float* __restrict__ Wkv,
        const float* __restrict__ wa, const float* __restrict__ wm,
        const float* __restrict__ wdk,
        const float* __restrict__ W0, const float* __restrict__ W1,
        const float* __restrict__ W2, const float* __restrict__ W3,
        unsigned* bar, float* lrg, float* momg, float* decg,
        unsigned short* snb, unsigned short* rnb,
        unsigned short* WTb, unsigned short* Wb, unsigned short* WqTb,
        unsigned short* WkvTb,
        unsigned short* xb0, unsigned short* xb1, unsigned short* xb2,
        unsigned short* xb3, unsigned short* vb,
        unsigned short* ds0, unsigned short* ds1, unsigned short* ds2,
        unsigned short* gbA, unsigned short* gbB,
        unsigned short* XT, unsigned short* GT,
        unsigned short* xq0, unsigned short* xq1,
        unsigned short* supb, float* out){
    const int tid = threadIdx.x, b = blockIdx.x;
    const int w = tid >> 6, lane = tid & 63;
    const int m16 = lane & 15, q16 = lane >> 4;
    __shared__ float ltile[32*33];    // transpose tile
    __shared__ float lcm[1024];       // S0 chunk-mean partials / S13 red
    __shared__ float lred[16];        // reductions / S13 rs

    // ---------------- S0: norms+gates (b<128) | weight prep (b>=128) ----------
    if (b < 128){
        int g = b;
        float cmp[4] = {0,0,0,0};
        for (int cc = 0; cc < 4; ++cc){
            int c = w*4 + cc;
            size_t tb_ = ((size_t)g*16 + c)*256;
            float x0 = seq[tb_ + lane],      x1 = seq[tb_ + lane + 64];
            float x2 = seq[tb_ + lane + 128], x3 = seq[tb_ + lane + 192];
            float ss = x0*x0 + x1*x1 + x2*x2 + x3*x3;
            #pragma unroll
            for (int off = 32; off; off >>= 1) ss += __shfl_xor(ss, off, 64);
            float r = rsqrtf(ss*(1.f/256.f) + EPSf);
            float s0 = x0*r*wsn[lane],     s1 = x1*r*wsn[lane+64];
            float s2 = x2*r*wsn[lane+128], s3 = x3*r*wsn[lane+192];
            snb[tb_ + lane]       = f2b(s0);
            snb[tb_ + lane + 64]  = f2b(s1);
            snb[tb_ + lane + 128] = f2b(s2);
            snb[tb_ + lane + 192] = f2b(s3);
            cmp[0] += s0; cmp[1] += s1; cmp[2] += s2; cmp[3] += s3;
            int tl = (g & 63)*16 + c;
            float r0 = 0.f, r1 = 0.f, r2 = 0.f, r3 = 0.f;
            if (tl <= 1008){
                size_t t2 = (((size_t)(g >> 6))*1024 + tl + 15)*256;
                float y0 = seq[t2 + lane],      y1 = seq[t2 + lane + 64];
                float y2 = seq[t2 + lane + 128], y3 = seq[t2 + lane + 192];
                float s2s = y0*y0 + y1*y1 + y2*y2 + y3*y3;
                #pragma unroll
                for (int off = 32; off; off >>= 1) s2s += __shfl_xor(s2s, off, 64);
                float rr = rsqrtf(s2s*(1.f/256.f) + EPSf);
                r0 = y0*rr*wrn[lane];     r1 = y1*rr*wrn[lane+64];
                r2 = y2*rr*wrn[lane+128]; r3 = y3*rr*wrn[lane+192];
            }
            rnb[tb_ + lane]       = f2b(r0);
            rnb[tb_ + lane + 64]  = f2b(r1);
            rnb[tb_ + lane + 128] = f2b(r2);
            rnb[tb_ + lane + 192] = f2b(r3);
        }
        #pragma unroll
        for (int k = 0; k < 4; ++k) lcm[w*256 + k*64 + lane] = cmp[k];
        __syncthreads();
        int d = tid;
        float cm = (lcm[d] + lcm[256+d] + lcm[512+d] + lcm[768+d]) * (1.f/16.f);
        float vals[3] = {cm*wa[d], cm*wm[d], cm*wdk[d]};
        float sums[3];
        #pragma unroll
        for (int q = 0; q < 3; ++q){
            float v = vals[q];
            #pragma unroll
            for (int off = 32; off; off >>= 1) v += __shfl_down(v, off, 64);
            if (lane == 0) lred[w] = v;
            __syncthreads();
            sums[q] = lred[0] + lred[1] + lred[2] + lred[3];
            __syncthreads();
        }
        if (tid == 0){
            lrg[g]  = sigm(sums[0]);
            momg[g] = sigm(sums[1]);
            decg[g] = sigm(sums[2]);
        }
    } else {
        int b2 = b - 128;
        for (int tj = b2; tj < 448; tj += 128){
            const float* S; unsigned short* T; int C; int t0;
            if (tj < 256){
                int z = tj >> 6; t0 = tj & 63;
                S = (z==0)?W0:(z==1)?W1:(z==2)?W2:W3;
                T = WTb + (size_t)z*DDn; C = 256;
            } else if (tj < 320){ t0 = tj - 256; S = Wq; T = WqTb; C = 256; }
            else { t0 = tj - 320; S = Wkv; T = WkvTb; C = 512; }
            int k0 = (t0 & 7)*32, j0 = (t0 >> 3)*32;
            int tx = tid & 31, ty = tid >> 5;
            __syncthreads();
            #pragma unroll
            for (int p = 0; p < 4; ++p)
                ltile[(ty + 8*p)*33 + tx] = S[(size_t)(k0 + ty + 8*p)*C + j0 + tx];
            __syncthreads();
            #pragma unroll
            for (int p = 0; p < 4; ++p)
                T[(size_t)(j0 + ty + 8*p)*256 + k0 + tx] = f2b(ltile[tx*33 + ty + 8*p]);
        }
        for (int i = b2*256 + tid; i < 98304; i += 32768){
            int z = i / 32768, off = i - z*32768;
            const float* S = (z==0)?W1:(z==1)?W2:W3;
            float2 v = *(const float2*)(S + (size_t)off*2);
            ushort2 u; u.x = f2b(v.x); u.y = f2b(v.y);
            *(ushort2*)(Wb + (size_t)z*DDn + (size_t)off*2) = u;
        }
    }
    gsync(bar);

    // ---------------- S1: kv-proj (+ q-proj) --------------------------------
    for (int j = b; j < 1536; j += 256){
        if (j < 1024){
            int g = j >> 3, n0 = (j & 7)*64 + w*16;
            f4v acc = mm_core(snb + (size_t)g*4096 + m16*256 + q16*8,
                              WkvTb + (size_t)(n0 + m16)*256 + q16*8);
            if (n0 < 256){
                ushort4 t4;
                #pragma unroll
                for (int r = 0; r < 4; ++r){
                    xb0[(size_t)g*4096 + (4*q16 + r)*256 + n0 + m16] = f2b(acc[r]);
                    ((unsigned short*)&t4)[r] = f2hu(acc[r]);
                }
                *(ushort4*)(XT + ((size_t)g*256 + n0 + m16)*16 + q16*4) = t4;
            } else {
                #pragma unroll
                for (int r = 0; r < 4; ++r)
                    vb[(size_t)g*4096 + (4*q16 + r)*256 + (n0 - 256) + m16] = f2hu(acc[r]);
            }
        } else {
            int j2 = j - 1024;
            int g = j2 >> 2, n0 = (j2 & 3)*64 + w*16;
            f4v acc = mm_core(rnb + (size_t)g*4096 + m16*256 + q16*8,
                              WqTb + (size_t)(n0 + m16)*256 + q16*8);
            #pragma unroll
            for (int r = 0; r < 4; ++r)
                xq0[(size_t)g*4096 + (4*q16 + r)*256 + n0 + m16] = f2b(acc[r]);
        }
    }
    gsync(bar);

    // ---------------- S2..S4: forward layers --------------------------------
    {
        const unsigned short* Xi[3] = {xb0, xb1, xb2};
        unsigned short* Xo[3] = {xb1, xb2, xb3};
        unsigned short* Ds[3] = {ds0, ds1, ds2};
        for (int l = 0; l < 3; ++l){
            for (int j = b; j < 512; j += 256){
                int g = j >> 2, n0 = (j & 3)*64 + w*16;
                f4v acc = mm_core(Xi[l] + (size_t)g*4096 + m16*256 + q16*8,
                                  WTb + (size_t)l*DDn + (size_t)(n0 + m16)*256 + q16*8);
                ushort4 t4;
                #pragma unroll
                for (int r = 0; r < 4; ++r){
                    float h = acc[r], s = sigm(h);
                    float sl = h*s, dv = s*(1.f + h*(1.f - s));
                    size_t ad = (size_t)g*4096 + (4*q16 + r)*256 + n0 + m16;
                    Xo[l][ad] = f2b(sl);
                    Ds[l][ad] = f2hu(dv);
                    ((unsigned short*)&t4)[r] = f2hu(sl);
                }
                *(ushort4*)(XT + (size_t)(l+1)*TB + ((size_t)g*256 + n0 + m16)*16 + q16*4) = t4;
            }
            gsync(bar);
        }
    }

    // ---------------- S5: pred -> G4 ----------------------------------------
    for (int j = b; j < 512; j += 256){
        int g = j >> 2, n0 = (j & 3)*64 + w*16;
        f4v acc = mm_core(xb3 + (size_t)g*4096 + m16*256 + q16*8,
                          WTb + (size_t)3*DDn + (size_t)(n0 + m16)*256 + q16*8);
        float sc = -2.f * lrg[g] * (1.f/256.f);
        ushort4 t4;
        #pragma unroll
        for (int r = 0; r < 4; ++r){
            size_t ad = (size_t)g*4096 + (4*q16 + r)*256 + n0 + m16;
            float gv = sc * (acc[r] - hu2f(vb[ad]));
            gbA[ad] = f2b(gv);
            ((unsigned short*)&t4)[r] = f2hu(gv);
        }
        *(ushort4*)(GT + (size_t)3*TB + ((size_t)g*256 + n0 + m16)*16 + q16*4) = t4;
    }
    gsync(bar);

    // ---------------- S6..S8: backward dgrads -------------------------------
    {
        const unsigned short* Gi[3] = {gbA, gbB, gbA};
        unsigned short* Go[3] = {gbB, gbA, nullptr};
        const unsigned short* Ds2[3] = {ds2, ds1, ds0};
        for (int s = 0; s < 3; ++s){
            int l = 2 - s;                       // weight W_{l+1} row-major at Wb[l]
            for (int j = b; j < 512; j += 256){
                int g = j >> 2, n0 = (j & 3)*64 + w*16;
                f4v acc = mm_core(Gi[s] + (size_t)g*4096 + m16*256 + q16*8,
                                  Wb + (size_t)l*DDn + (size_t)(n0 + m16)*256 + q16*8);
                ushort4 t4;
                #pragma unroll
                for (int r = 0; r < 4; ++r){
                    size_t ad = (size_t)g*4096 + (4*q16 + r)*256 + n0 + m16;
                    float gv = acc[r] * hu2f(Ds2[s][ad]);
                    if (Go[s]) Go[s][ad] = f2b(gv);
                    ((unsigned short*)&t4)[r] = f2hu(gv);
                }
                *(ushort4*)(GT + (size_t)l*TB + ((size_t)g*256 + n0 + m16)*16 + q16*4) = t4;
            }
            gsync(bar);
        }
    }

    // ---------------- S9: outer-product + scans -> supb ---------------------
    {
        int wv = b*4 + w;
        for (int rep = 0; rep < 2; ++rep){
            int job = wv + rep*1024;
            int bq = job >> 10, rem = job & 1023;
            int l = rem >> 8, rem2 = rem & 255;
            int o0 = (rem2 >> 4)*16, d0 = (rem2 & 15)*16;
            const unsigned short* xbase = XT + (size_t)l*TB
                + (((size_t)bq*64)*256 + d0 + m16)*16 + q16*4;
            const unsigned short* gbase = GT + (size_t)l*TB
                + (((size_t)bq*64)*256 + o0 + m16)*16 + q16*4;
            float ms[4] = {0,0,0,0}, us[4] = {0,0,0,0};
            h4 xa = ldh4(xbase), gb2 = ldh4(gbase);
            for (int n = 0; n < 64; ++n){
                int gg = bq*64 + n;
                h4 xan, gbn;
                if (n < 63){
                    xan = ldh4(xbase + (size_t)(n+1)*4096);
                    gbn = ldh4(gbase + (size_t)(n+1)*4096);
                }
                f4v z = {0.f,0.f,0.f,0.f};
                f4v s = __builtin_amdgcn_mfma_f32_16x16x16f16(xa, gb2, z, 0, 0, 0);
                float mo = momg[gg], de = 1.f - decg[gg];
                ushort4 u4;
                #pragma unroll
                for (int r = 0; r < 4; ++r){
                    ms[r] = mo*ms[r] + s[r];
                    us[r] = de*us[r] + ms[r];
                    ((unsigned short*)&u4)[r] = f2b(us[r]);
                }
                *(ushort4*)(supb + ((size_t)gg*4 + l)*DDn
                            + (size_t)(o0 + m16)*256 + d0 + q16*4) = u4;
                xa = xan; gb2 = gbn;
            }
        }
    }
    gsync(bar);

    // ---------------- S10..S12: retrieval layers 0..2 -----------------------
    {
        const unsigned short* Xi[3] = {xq0, xq1, xq0};
        unsigned short* Xo[3] = {xq1, xq0, xq1};
        for (int l = 0; l < 3; ++l){
            for (int j = b; j < 512; j += 256){
                int g = j >> 2, n0 = (j & 3)*64 + w*16;
                const unsigned short* ar = Xi[l] + (size_t)g*4096 + m16*256 + q16*8;
                s8v a[8];
                #pragma unroll
                for (int i = 0; i < 8; ++i) a[i] = *(const s8v*)(ar + i*32);
                f4v acc = {0.f,0.f,0.f,0.f};
                const unsigned short* bw = WTb + (size_t)l*DDn
                    + (size_t)(n0 + m16)*256 + q16*8;
                const unsigned short* bu = supb + (size_t)g*PPn + (size_t)l*DDn
                    + (size_t)(n0 + m16)*256 + q16*8;
                #pragma unroll
                for (int i = 0; i < 8; ++i){
                    s8v bW = *(const s8v*)(bw + i*32);
                    s8v bU = *(const s8v*)(bu + i*32);
                    acc = __builtin_amdgcn_mfma_f32_16x16x32_bf16(a[i], bW, acc, 0, 0, 0);
                    acc = __builtin_amdgcn_mfma_f32_16x16x32_bf16(a[i], bU, acc, 0, 0, 0);
                }
                #pragma unroll
                for (int r = 0; r < 4; ++r)
                    Xo[l][(size_t)g*4096 + (4*q16 + r)*256 + n0 + m16] = f2b(silu_(acc[r]));
            }
            gsync(bar);
        }
    }

    // ---------------- S13: last layer + post-norm + shift -------------------
    for (int j = b; j < 128; j += 256){
        int g = j, bq = g >> 6, nl = g & 63;
        s8v a[8];
        const unsigned short* ar = xq1 + (size_t)g*4096 + m16*256 + q16*8;
        #pragma unroll
        for (int i = 0; i < 8; ++i) a[i] = *(const s8v*)(ar + i*32);
        f4v acc[4];
        #pragma unroll
        for (int t = 0; t < 4; ++t){
            int n0 = w*64 + t*16;
            f4v ac = {0.f,0.f,0.f,0.f};
            const unsigned short* bw = WTb + (size_t)3*DDn
                + (size_t)(n0 + m16)*256 + q16*8;
            const unsigned short* bu = supb + (size_t)g*PPn + (size_t)3*DDn
                + (size_t)(n0 + m16)*256 + q16*8;
            #pragma unroll
            for (int i = 0; i < 8; ++i){
                s8v bW = *(const s8v*)(bw + i*32);
                s8v bU = *(const s8v*)(bu + i*32);
                ac = __builtin_amdgcn_mfma_f32_16x16x32_bf16(a[i], bW, ac, 0, 0, 0);
                ac = __builtin_amdgcn_mfma_f32_16x16x32_bf16(a[i], bU, ac, 0, 0, 0);
            }
            acc[t] = ac;
        }
        float part[4] = {0,0,0,0};
        #pragma unroll
        for (int t = 0; t < 4; ++t)
            #pragma unroll
            for (int r = 0; r < 4; ++r) part[r] += acc[t][r]*acc[t][r];
        #pragma unroll
        for (int off = 1; off < 16; off <<= 1)
            #pragma unroll
            for (int r = 0; r < 4; ++r) part[r] += __shfl_xor(part[r], off, 64);
        if (m16 == 0)
            #pragma unroll
            for (int r = 0; r < 4; ++r) lcm[w*16 + 4*q16 + r] = part[r];
        __syncthreads();
        if (tid < 16){
            float s = lcm[tid] + lcm[16 + tid] + lcm[32 + tid] + lcm[48 + tid];
            lred[tid] = rsqrtf(s*(1.f/256.f) + EPSf);
        }
        __syncthreads();
        #pragma unroll
        for (int t = 0; t < 4; ++t){
            int d = w*64 + t*16 + m16;
            float wp = wpost[d];
            #pragma unroll
            for (int r = 0; r < 4; ++r){
                int c = 4*q16 + r;
                int tp = nl*16 + c + 15;
                if (tp < 1024)
                    out[((size_t)bq*1024 + tp)*256 + d] = acc[t][r]*lred[c]*wp;
            }
        }
        if (nl == 0){
            for (int idx = tid; idx < 15*256; idx += 256)
                out[(size_t)bq*262144 + idx] = 0.f;
        }
    }
}

extern "C" void kernel_launch(void* const* d_in, const int* in_sizes, int n_in,
                              void* d_out, int out_size, void* d_ws, size_t ws_size,
                              hipStream_t stream) {
    const float* seq     = (const float*)d_in[0];
    const float* w_store = (const float*)d_in[1];
    const float* w_retr  = (const float*)d_in[2];
    const float* w_post  = (const float*)d_in[3];
    const float* Wq      = (const float*)d_in[4];
    const float* Wkv     = (const float*)d_in[5];
    const float* w_adapt = (const float*)d_in[6];
    const float* w_mom   = (const float*)d_in[7];
    const float* w_decay = (const float*)d_in[8];
    const float* W0      = (const float*)d_in[9];
    const float* W1      = (const float*)d_in[10];
    const float* W2      = (const float*)d_in[11];
    const float* W3      = (const float*)d_in[12];

    unsigned* bar = (unsigned*)d_ws;                       // 256 B, zeroed below
    float* lrg  = (float*)((char*)d_ws + 256);             // 128
    float* momg = lrg + NCn;
    float* decg = momg + NCn;
    unsigned short* p = (unsigned short*)(decg + NCn);     // byte off 1792, 16B-aligned
    unsigned short* snb   = p;            p += TB;
    unsigned short* rnb   = p;            p += TB;
    unsigned short* WTb   = p;            p += 4*(size_t)DDn;
    unsigned short* Wb    = p;            p += 3*(size_t)DDn;
    unsigned short* WqTb  = p;            p += (size_t)DDn;
    unsigned short* WkvTb = p;            p += 2*(size_t)DDn;
    unsigned short* xb0   = p;            p += TB;
    unsigned short* xb1   = p;            p += TB;
    unsigned short* xb2   = p;            p += TB;
    unsigned short* xb3   = p;            p += TB;
    unsigned short* vb    = p;            p += TB;
    unsigned short* ds0   = p;            p += TB;
    unsigned short* ds1   = p;            p += TB;
    unsigned short* ds2   = p;            p += TB;
    unsigned short* gbA   = p;            p += TB;
    unsigned short* gbB   = p;            p += TB;
    unsigned short* XT    = p;            p += 4*TB;
    unsigned short* GT    = p;            p += 4*TB;
    unsigned short* xq0   = p;            p += TB;
    unsigned short* xq1   = p;            p += TB;
    unsigned short* supb  = p;                             // 64*TB (67MB)

    hipMemsetAsync(bar, 0, 256, stream);
    kchain<<<dim3(256), 256, 0, stream>>>(
        seq, w_store, w_retr, w_post, Wq, Wkv, w_adapt, w_mom, w_decay,
        W0, W1, W2, W3, bar, lrg, momg, decg,
        snb, rnb, WTb, Wb, WqTb, WkvTb,
        xb0, xb1, xb2, xb3, vb, ds0, ds1, ds2, gbA, gbB,
        XT, GT, xq0, xq1, supb, (float*)d_out);
}

// Round 10
// 213.178 us; speedup vs baseline: 2.3990x; 2.3990x over previous
//
#include <hip/hip_runtime.h>
#include <hip/hip_bf16.h>

typedef __attribute__((ext_vector_type(8)))  short s8v;   // 8 bf16
typedef __attribute__((ext_vector_type(4)))  float f4v;   // 16x16 C/D
typedef _Float16 h4 __attribute__((ext_vector_type(4)));  // 4 f16

constexpr int Dd   = 256;
constexpr int NCn  = 128;
constexpr int DDn  = 65536;
constexpr int PPn  = 4 * DDn;
constexpr size_t TB = (size_t)NCn * 4096;
constexpr int XP   = 264;             // padded LDS row (bf16 elems)
constexpr float EPSf = 1.1920929e-07f;

__device__ __forceinline__ float sigm(float x){ return 1.0f/(1.0f + expf(-x)); }
__device__ __forceinline__ float silu_(float x){ return x * sigm(x); }

__device__ __forceinline__ unsigned short f2b(float x){
    __hip_bfloat16 b = __float2bfloat16(x);
    unsigned short u; __builtin_memcpy(&u, &b, 2); return u;
}
__device__ __forceinline__ float b2f(unsigned short u){
    __hip_bfloat16 b; __builtin_memcpy(&b, &u, 2); return __bfloat162float(b);
}
__device__ __forceinline__ unsigned short f2hu(float x){
    _Float16 h = (_Float16)x;
    unsigned short u; __builtin_memcpy(&u, &h, 2); return u;
}
__device__ __forceinline__ float hu2f(unsigned short u){
    _Float16 h; __builtin_memcpy(&h, &u, 2); return (float)h;
}
__device__ __forceinline__ h4 ldh4(const unsigned short* p){
    h4 r; __builtin_memcpy(&r, p, 8); return r;
}

// ---- merged prep: b<128 chunk norms+gates (per-wave shuffle); b>=128 weight prep ----
__global__ __launch_bounds__(256) void kprep(const float* __restrict__ seq,
        const float* __restrict__ wsn, const float* __restrict__ wrn,
        const float* __restrict__ wa, const float* __restrict__ wm,
        const float* __restrict__ wdk,
        const float* __restrict__ Wq, const float* __restrict__ Wkv,
        const float* __restrict__ W0, const float* __restrict__ W1,
        const float* __restrict__ W2, const float* __restrict__ W3,
        unsigned short* __restrict__ snb, unsigned short* __restrict__ rnb,
        unsigned short* __restrict__ WTb, unsigned short* __restrict__ Wb,
        unsigned short* __restrict__ WqTb, unsigned short* __restrict__ WkvTb,
        float* __restrict__ lrg, float* __restrict__ momg, float* __restrict__ decg){
    __shared__ float ltile[32*33];
    __shared__ float lcm[1024];
    __shared__ float lred[4];
    int tid = threadIdx.x, b = blockIdx.x;
    int w = tid >> 6, lane = tid & 63;
    if (b < 128){
        int g = b;
        float cmp[4] = {0,0,0,0};
        for (int cc = 0; cc < 4; ++cc){
            int c = w*4 + cc;
            size_t tb_ = ((size_t)g*16 + c)*256;
            float x0 = seq[tb_ + lane],       x1 = seq[tb_ + lane + 64];
            float x2 = seq[tb_ + lane + 128], x3 = seq[tb_ + lane + 192];
            float ss = x0*x0 + x1*x1 + x2*x2 + x3*x3;
            #pragma unroll
            for (int off = 32; off; off >>= 1) ss += __shfl_xor(ss, off, 64);
            float r = rsqrtf(ss*(1.f/256.f) + EPSf);
            float s0 = x0*r*wsn[lane],     s1 = x1*r*wsn[lane+64];
            float s2 = x2*r*wsn[lane+128], s3 = x3*r*wsn[lane+192];
            snb[tb_ + lane]       = f2b(s0);
            snb[tb_ + lane + 64]  = f2b(s1);
            snb[tb_ + lane + 128] = f2b(s2);
            snb[tb_ + lane + 192] = f2b(s3);
            cmp[0] += s0; cmp[1] += s1; cmp[2] += s2; cmp[3] += s3;
            int tl = (g & 63)*16 + c;
            float r0 = 0.f, r1 = 0.f, r2 = 0.f, r3 = 0.f;
            if (tl <= 1008){
                size_t t2 = (((size_t)(g >> 6))*1024 + tl + 15)*256;
                float y0 = seq[t2 + lane],       y1 = seq[t2 + lane + 64];
                float y2 = seq[t2 + lane + 128], y3 = seq[t2 + lane + 192];
                float s2s = y0*y0 + y1*y1 + y2*y2 + y3*y3;
                #pragma unroll
                for (int off = 32; off; off >>= 1) s2s += __shfl_xor(s2s, off, 64);
                float rr = rsqrtf(s2s*(1.f/256.f) + EPSf);
                r0 = y0*rr*wrn[lane];     r1 = y1*rr*wrn[lane+64];
                r2 = y2*rr*wrn[lane+128]; r3 = y3*rr*wrn[lane+192];
            }
            rnb[tb_ + lane]       = f2b(r0);
            rnb[tb_ + lane + 64]  = f2b(r1);
            rnb[tb_ + lane + 128] = f2b(r2);
            rnb[tb_ + lane + 192] = f2b(r3);
        }
        #pragma unroll
        for (int k = 0; k < 4; ++k) lcm[w*256 + k*64 + lane] = cmp[k];
        __syncthreads();
        int d = tid;
        float cm = (lcm[d] + lcm[256+d] + lcm[512+d] + lcm[768+d]) * (1.f/16.f);
        float vals[3] = {cm*wa[d], cm*wm[d], cm*wdk[d]};
        float sums[3];
        #pragma unroll
        for (int q = 0; q < 3; ++q){
            float v = vals[q];
            #pragma unroll
            for (int off = 32; off; off >>= 1) v += __shfl_down(v, off, 64);
            if (lane == 0) lred[w] = v;
            __syncthreads();
            sums[q] = lred[0] + lred[1] + lred[2] + lred[3];
            __syncthreads();
        }
        if (tid == 0){
            lrg[g]  = sigm(sums[0]);
            momg[g] = sigm(sums[1]);
            decg[g] = sigm(sums[2]);
        }
    } else {
        int b2 = b - 128;   // 0..31
        for (int tj = b2; tj < 448; tj += 32){
            const float* S; unsigned short* T; int C; int t0;
            if (tj < 256){
                int z = tj >> 6; t0 = tj & 63;
                S = (z==0)?W0:(z==1)?W1:(z==2)?W2:W3;
                T = WTb + (size_t)z*DDn; C = 256;
            } else if (tj < 320){ t0 = tj - 256; S = Wq; T = WqTb; C = 256; }
            else { t0 = tj - 320; S = Wkv; T = WkvTb; C = 512; }
            int k0 = (t0 & 7)*32, j0 = (t0 >> 3)*32;
            int tx = tid & 31, ty = tid >> 5;
            __syncthreads();
            #pragma unroll
            for (int p = 0; p < 4; ++p)
                ltile[(ty + 8*p)*33 + tx] = S[(size_t)(k0 + ty + 8*p)*C + j0 + tx];
            __syncthreads();
            #pragma unroll
            for (int p = 0; p < 4; ++p)
                T[(size_t)(j0 + ty + 8*p)*256 + k0 + tx] = f2b(ltile[tx*33 + ty + 8*p]);
        }
        for (int i = b2*256 + tid; i < 98304; i += 8192){
            int z = i / 32768, off = i - z*32768;
            const float* S = (z==0)?W1:(z==1)?W2:W3;
            float2 v = *(const float2*)(S + (size_t)off*2);
            ushort2 u; u.x = f2b(v.x); u.y = f2b(v.y);
            *(ushort2*)(Wb + (size_t)z*DDn + (size_t)off*2) = u;
        }
    }
}

// ---- fwd + bwd dgrads (+ q-proj slice); writes f16 XT (bh=0), f16 GT (bh=1) ----
// grid (3, 128): bh=0 fwd->XT, bh=1 fwd+bwd->GT, bh=2 q-proj->xq0
__global__ __launch_bounds__(512, 1) void kfb(const unsigned short* __restrict__ snb,
        const unsigned short* __restrict__ rnb,
        const unsigned short* __restrict__ WkvTb, const unsigned short* __restrict__ WTb,
        const unsigned short* __restrict__ Wb, const unsigned short* __restrict__ WqTb,
        const float* __restrict__ lrg,
        unsigned short* __restrict__ XT, unsigned short* __restrict__ GT,
        unsigned short* __restrict__ xq0){
    __shared__ unsigned short xl[4][16][XP];
    __shared__ unsigned short Gs[16][XP];
    int tid = threadIdx.x, w = tid >> 6, lane = tid & 63;
    int m16 = lane & 15, q16 = lane >> 4;
    int g = blockIdx.y, bh = blockIdx.x;

    if (bh == 2){   // q projection, no LDS, exits early
        s8v a[8];
        const unsigned short* ar = rnb + (size_t)g*4096 + m16*256 + q16*8;
        #pragma unroll
        for (int i = 0; i < 8; ++i) a[i] = *(const s8v*)(ar + i*32);
        #pragma unroll
        for (int t = 0; t < 2; ++t){
            int n0 = w*32 + t*16;
            f4v acc = {0.f,0.f,0.f,0.f};
            const unsigned short* bw = WqTb + (size_t)(n0 + m16)*256 + q16*8;
            #pragma unroll
            for (int i = 0; i < 8; ++i){
                s8v bb = *(const s8v*)(bw + i*32);
                acc = __builtin_amdgcn_mfma_f32_16x16x32_bf16(a[i], bb, acc, 0, 0, 0);
            }
            #pragma unroll
            for (int r = 0; r < 4; ++r)
                xq0[(size_t)g*4096 + (4*q16 + r)*256 + n0 + m16] = f2b(acc[r]);
        }
        return;
    }

    float sc = -2.f * lrg[g] * (1.f/256.f);
    s8v af[8];
    const unsigned short* arow = snb + (size_t)g*4096 + m16*256 + q16*8;
    #pragma unroll
    for (int i = 0; i < 8; ++i) af[i] = *(const s8v*)(arow + i*32);

    f4v vacc[2];
    #pragma unroll
    for (int t = 0; t < 2; ++t){
        int n0 = w*32 + t*16;
        f4v ka = {0.f,0.f,0.f,0.f}, va = {0.f,0.f,0.f,0.f};
        const unsigned short* brK = WkvTb + (size_t)(n0 + m16)*256 + q16*8;
        const unsigned short* brV = WkvTb + (size_t)(256 + n0 + m16)*256 + q16*8;
        #pragma unroll
        for (int i = 0; i < 8; ++i){
            s8v bK = *(const s8v*)(brK + i*32);
            s8v bV = *(const s8v*)(brV + i*32);
            ka = __builtin_amdgcn_mfma_f32_16x16x32_bf16(af[i], bK, ka, 0, 0, 0);
            va = __builtin_amdgcn_mfma_f32_16x16x32_bf16(af[i], bV, va, 0, 0, 0);
        }
        vacc[t] = va;
        #pragma unroll
        for (int r = 0; r < 4; ++r) xl[0][4*q16 + r][n0 + m16] = f2b(ka[r]);
    }

    f4v hreg[3][2];
    for (int l = 0; l < 3; ++l){
        __syncthreads();
        s8v xa[8];
        #pragma unroll
        for (int i = 0; i < 8; ++i)
            xa[i] = *(const s8v*)(&xl[l][m16][q16*8 + i*32]);
        const unsigned short* Wt = WTb + (size_t)l*DDn;
        #pragma unroll
        for (int t = 0; t < 2; ++t){
            int n0 = w*32 + t*16;
            f4v acc = {0.f,0.f,0.f,0.f};
            const unsigned short* br = Wt + (size_t)(n0 + m16)*256 + q16*8;
            #pragma unroll
            for (int i = 0; i < 8; ++i){
                s8v b = *(const s8v*)(br + i*32);
                acc = __builtin_amdgcn_mfma_f32_16x16x32_bf16(xa[i], b, acc, 0, 0, 0);
            }
            hreg[l][t] = acc;
            #pragma unroll
            for (int r = 0; r < 4; ++r)
                xl[l+1][4*q16 + r][n0 + m16] = f2b(silu_(acc[r]));
        }
    }
    __syncthreads();

    if (bh == 0){   // write f16 transposed activations XT[l][g][d][c]
        int d = tid & 255, half = tid >> 8;
        #pragma unroll
        for (int l = 0; l < 4; ++l){
            s8v v;
            #pragma unroll
            for (int j = 0; j < 8; ++j)
                v[j] = (short)f2hu(b2f(xl[l][half*8 + j][d]));
            *(s8v*)(XT + (((size_t)l*128 + g)*256 + d)*16 + half*8) = v;
        }
        return;
    }

    {   // layer 3 (pred) -> G4
        s8v xa[8];
        #pragma unroll
        for (int i = 0; i < 8; ++i)
            xa[i] = *(const s8v*)(&xl[3][m16][q16*8 + i*32]);
        const unsigned short* Wt = WTb + (size_t)3*DDn;
        #pragma unroll
        for (int t = 0; t < 2; ++t){
            int n0 = w*32 + t*16;
            f4v acc = {0.f,0.f,0.f,0.f};
            const unsigned short* br = Wt + (size_t)(n0 + m16)*256 + q16*8;
            #pragma unroll
            for (int i = 0; i < 8; ++i){
                s8v b = *(const s8v*)(br + i*32);
                acc = __builtin_amdgcn_mfma_f32_16x16x32_bf16(xa[i], b, acc, 0, 0, 0);
            }
            #pragma unroll
            for (int r = 0; r < 4; ++r)
                Gs[4*q16 + r][n0 + m16] = f2b(sc * (acc[r] - vacc[t][r]));
        }
    }
    __syncthreads();
    {
        int d = tid & 255, half = tid >> 8;
        s8v v;
        #pragma unroll
        for (int j = 0; j < 8; ++j)
            v[j] = (short)f2hu(b2f(Gs[half*8 + j][d]));
        *(s8v*)(GT + (((size_t)3*128 + g)*256 + d)*16 + half*8) = v;
    }

    for (int l = 3; l >= 1; --l){
        s8v gfa[8];
        #pragma unroll
        for (int i = 0; i < 8; ++i)
            gfa[i] = *(const s8v*)(&Gs[m16][q16*8 + i*32]);
        const unsigned short* Wr = Wb + (size_t)(l-1)*DDn;
        f4v gn[2];
        #pragma unroll
        for (int t = 0; t < 2; ++t){
            int n0 = w*32 + t*16;
            f4v acc = {0.f,0.f,0.f,0.f};
            const unsigned short* br = Wr + (size_t)(n0 + m16)*256 + q16*8;
            #pragma unroll
            for (int i = 0; i < 8; ++i){
                s8v b = *(const s8v*)(br + i*32);
                acc = __builtin_amdgcn_mfma_f32_16x16x32_bf16(gfa[i], b, acc, 0, 0, 0);
            }
            #pragma unroll
            for (int r = 0; r < 4; ++r){
                float s = sigm(hreg[l-1][t][r]);
                float dv = s*(1.f + hreg[l-1][t][r]*(1.f - s));
                gn[t][r] = acc[r] * dv;
            }
        }
        __syncthreads();
        #pragma unroll
        for (int t = 0; t < 2; ++t){
            int n0 = w*32 + t*16;
            #pragma unroll
            for (int r = 0; r < 4; ++r)
                Gs[4*q16 + r][n0 + m16] = f2b(gn[t][r]);
        }
        __syncthreads();
        {
            int d = tid & 255, half = tid >> 8;
            s8v v;
            #pragma unroll
            for (int j = 0; j < 8; ++j)
                v[j] = (short)f2hu(b2f(Gs[half*8 + j][d]));
            *(s8v*)(GT + (((size_t)(l-1)*128 + g)*256 + d)*16 + half*8) = v;
        }
    }
}

// ---- fused outer-product + scans -> updates (bf16), vectorized stores ----
// A = X^T (m = d_in), B = G^T (n = d_out): store [g][l][d_out][d_in] as ushort4
__global__ __launch_bounds__(64, 1) void kupd(const unsigned short* __restrict__ XT,
        const unsigned short* __restrict__ GT, const float* __restrict__ momg,
        const float* __restrict__ decg, unsigned short* __restrict__ supb){
    int lane = threadIdx.x, m16 = lane & 15, q16 = lane >> 4;
    int l = blockIdx.z & 3, b = blockIdx.z >> 2;
    int d0 = blockIdx.x*16, o0 = blockIdx.y*16;
    const unsigned short* xbase = XT + (((size_t)l*128 + b*64)*256 + d0 + m16)*16 + q16*4;
    const unsigned short* gbase = GT + (((size_t)l*128 + b*64)*256 + o0 + m16)*16 + q16*4;
    float ms[4] = {0,0,0,0}, us[4] = {0,0,0,0};
    h4 xa = ldh4(xbase);
    h4 gb = ldh4(gbase);
    for (int n = 0; n < 64; ++n){
        int gg = b*64 + n;
        h4 xan, gbn;
        if (n < 63){
            xan = ldh4(xbase + (size_t)(n+1)*4096);
            gbn = ldh4(gbase + (size_t)(n+1)*4096);
        }
        f4v z = {0.f,0.f,0.f,0.f};
        f4v s = __builtin_amdgcn_mfma_f32_16x16x16f16(xa, gb, z, 0, 0, 0);
        float mo = momg[gg], de = 1.f - decg[gg];
        ushort4 u4;
        #pragma unroll
        for (int r = 0; r < 4; ++r){
            ms[r] = mo*ms[r] + s[r];
            us[r] = de*us[r] + ms[r];
            ((unsigned short*)&u4)[r] = f2b(us[r]);
        }
        *(ushort4*)(supb + ((size_t)gg*4 + l)*DDn + (size_t)(o0 + m16)*256
                    + d0 + q16*4) = u4;
        xa = xan; gb = gbn;
    }
}

// ---- one retrieval MLP layer, streaming, no barriers, no LDS ----
__global__ __launch_bounds__(256, 1) void klayer(const unsigned short* __restrict__ Xin,
        const unsigned short* __restrict__ Wt, const unsigned short* __restrict__ supb,
        int l, unsigned short* __restrict__ Xout){
    int lane = threadIdx.x & 63, w = threadIdx.x >> 6;
    int m16 = lane & 15, q16 = lane >> 4;
    int g = blockIdx.y, n0 = blockIdx.x*64 + w*16;
    s8v a[8];
    const unsigned short* ar = Xin + (size_t)g*4096 + m16*256 + q16*8;
    #pragma unroll
    for (int i = 0; i < 8; ++i) a[i] = *(const s8v*)(ar + i*32);
    f4v acc = {0.f,0.f,0.f,0.f};
    const unsigned short* bw = Wt + (size_t)(n0 + m16)*256 + q16*8;
    const unsigned short* bu = supb + (size_t)l*DDn + (size_t)g*PPn
                               + (size_t)(n0 + m16)*256 + q16*8;
    #pragma unroll
    for (int i = 0; i < 8; ++i){
        s8v bW = *(const s8v*)(bw + i*32);
        s8v bU = *(const s8v*)(bu + i*32);
        acc = __builtin_amdgcn_mfma_f32_16x16x32_bf16(a[i], bW, acc, 0, 0, 0);
        acc = __builtin_amdgcn_mfma_f32_16x16x32_bf16(a[i], bU, acc, 0, 0, 0);
    }
    #pragma unroll
    for (int r = 0; r < 4; ++r)
        Xout[(size_t)g*4096 + (4*q16 + r)*256 + n0 + m16] = f2b(silu_(acc[r]));
}

// ---- final fast-weight layer + post rmsnorm + shift + zero rows, fused ----
__global__ __launch_bounds__(256, 1) void klast(const unsigned short* __restrict__ Xin,
        const unsigned short* __restrict__ Wt, const unsigned short* __restrict__ supb,
        const float* __restrict__ wpost, float* __restrict__ out){
    __shared__ float red[4][16];
    __shared__ float rs[16];
    int tid = threadIdx.x, w = tid >> 6, lane = tid & 63;
    int m16 = lane & 15, q16 = lane >> 4;
    int g = blockIdx.x, b = g >> 6, nl = g & 63;
    s8v a[8];
    const unsigned short* ar = Xin + (size_t)g*4096 + m16*256 + q16*8;
    #pragma unroll
    for (int i = 0; i < 8; ++i) a[i] = *(const s8v*)(ar + i*32);
    f4v acc[4];
    #pragma unroll
    for (int t = 0; t < 4; ++t){
        int n0 = w*64 + t*16;
        f4v ac = {0.f,0.f,0.f,0.f};
        const unsigned short* bw = Wt + (size_t)(n0 + m16)*256 + q16*8;
        const unsigned short* bu = supb + (size_t)3*DDn + (size_t)g*PPn
                                   + (size_t)(n0 + m16)*256 + q16*8;
        #pragma unroll
        for (int i = 0; i < 8; ++i){
            s8v bW = *(const s8v*)(bw + i*32);
            s8v bU = *(const s8v*)(bu + i*32);
            ac = __builtin_amdgcn_mfma_f32_16x16x32_bf16(a[i], bW, ac, 0, 0, 0);
            ac = __builtin_amdgcn_mfma_f32_16x16x32_bf16(a[i], bU, ac, 0, 0, 0);
        }
        acc[t] = ac;
    }
    float part[4] = {0,0,0,0};
    #pragma unroll
    for (int t = 0; t < 4; ++t)
        #pragma unroll
        for (int r = 0; r < 4; ++r) part[r] += acc[t][r]*acc[t][r];
    #pragma unroll
    for (int off = 1; off < 16; off <<= 1)
        #pragma unroll
        for (int r = 0; r < 4; ++r) part[r] += __shfl_xor(part[r], off, 64);
    if (m16 == 0)
        #pragma unroll
        for (int r = 0; r < 4; ++r) red[w][4*q16 + r] = part[r];
    __syncthreads();
    if (tid < 16){
        float s = red[0][tid] + red[1][tid] + red[2][tid] + red[3][tid];
        rs[tid] = rsqrtf(s*(1.f/256.f) + EPSf);
    }
    __syncthreads();
    #pragma unroll
    for (int t = 0; t < 4; ++t){
        int d = w*64 + t*16 + m16;
        float wp = wpost[d];
        #pragma unroll
        for (int r = 0; r < 4; ++r){
            int c = 4*q16 + r;
            int tp = nl*16 + c + 15;
            if (tp < 1024)
                out[((size_t)b*1024 + tp)*256 + d] = acc[t][r]*rs[c]*wp;
        }
    }
    if (nl == 0){
        for (int idx = tid; idx < 15*256; idx += 256)
            out[(size_t)b*262144 + idx] = 0.f;
    }
}

extern "C" void kernel_launch(void* const* d_in, const int* in_sizes, int n_in,
                              void* d_out, int out_size, void* d_ws, size_t ws_size,
                              hipStream_t stream) {
    const float* seq     = (const float*)d_in[0];
    const float* w_store = (const float*)d_in[1];
    const float* w_retr  = (const float*)d_in[2];
    const float* w_post  = (const float*)d_in[3];
    const float* Wq      = (const float*)d_in[4];
    const float* Wkv     = (const float*)d_in[5];
    const float* w_adapt = (const float*)d_in[6];
    const float* w_mom   = (const float*)d_in[7];
    const float* w_decay = (const float*)d_in[8];
    const float* W0      = (const float*)d_in[9];
    const float* W1      = (const float*)d_in[10];
    const float* W2      = (const float*)d_in[11];
    const float* W3      = (const float*)d_in[12];

    float* lrg   = (float*)d_ws;                  // 128
    float* momg  = lrg + NCn;
    float* decg  = momg + NCn;
    unsigned short* p = (unsigned short*)(decg + NCn + 32);
    unsigned short* snb   = p;            p += TB;
    unsigned short* rnb   = p;            p += TB;
    unsigned short* WTb   = p;            p += 4*(size_t)DDn;
    unsigned short* Wb    = p;            p += 3*(size_t)DDn;
    unsigned short* WqTb  = p;            p += (size_t)DDn;
    unsigned short* WkvTb = p;            p += 2*(size_t)DDn;
    unsigned short* XT    = p;            p += 4*TB;   // f16
    unsigned short* GT    = p;            p += 4*TB;   // f16
    unsigned short* xq0   = p;            p += TB;
    unsigned short* xq1   = p;            p += TB;
    unsigned short* supb  = p;                          // 64*TB bf16 (67MB)

    kprep <<<dim3(160),      256, 0, stream>>>(seq, w_store, w_retr,
                                               w_adapt, w_mom, w_decay,
                                               Wq, Wkv, W0, W1, W2, W3,
                                               snb, rnb, WTb, Wb, WqTb, WkvTb,
                                               lrg, momg, decg);
    kfb   <<<dim3(3, NCn),   512, 0, stream>>>(snb, rnb, WkvTb, WTb, Wb, WqTb,
                                               lrg, XT, GT, xq0);
    kupd  <<<dim3(16, 16, 8), 64, 0, stream>>>(XT, GT, momg, decg, supb);
    klayer<<<dim3(4, NCn),   256, 0, stream>>>(xq0, WTb + 0*(size_t)DDn, supb, 0, xq1);
    klayer<<<dim3(4, NCn),   256, 0, stream>>>(xq1, WTb + 1*(size_t)DDn, supb, 1, xq0);
    klayer<<<dim3(4, NCn),   256, 0, stream>>>(xq0, WTb + 2*(size_t)DDn, supb, 2, xq1);
    klast <<<dim3(NCn),      256, 0, stream>>>(xq1, WTb + 3*(size_t)DDn, supb,
                                               w_post, (float*)d_out);
}